// Round 1
// baseline (1032.952 us; speedup 1.0000x reference)
//
#include <hip/hip_runtime.h>
#include <hip/hip_bf16.h>

// LSTM: B=512, T=512, I=128, H=50, O=10, fp32.
// Plan: [xproj GEMM: xp[t][b][200] = x[b][t][:] . W_ih[g][:]] -> [per-batch
// recurrence, 1 wave/block, gates i,f,g,o for hidden k all in thread k] -> [FC].

#define BB 512
#define TT 512
#define II 128
#define HH 50
#define GG 200   // 4*H

__device__ __forceinline__ float fsig(float x) {
    return 1.f / (1.f + __expf(-x));
}
__device__ __forceinline__ float ftanh(float x) {
    float e = __expf(-2.f * fabsf(x));
    float t = (1.f - e) / (1.f + e);
    return (x >= 0.f) ? t : -t;
}

// ---------------- Kernel 1: input projection ----------------
// Block: 256 threads, 32 rows (t_local*512 + b) x 200 cols.
// x tile staged transposed in LDS [i][r] (pad 36) so inner reads are
// same-address broadcasts (conflict-free).
__global__ __launch_bounds__(256) void xproj_kernel(
    const float* __restrict__ x, const float* __restrict__ W_ih,
    float* __restrict__ xp, int t0)
{
    __shared__ __align__(16) float xt[128][36];
    const int tid = threadIdx.x;
    const int row0 = blockIdx.x * 32;     // row = tl*512 + b  (32 | 512, no straddle)
    const int tl = row0 >> 9;
    const int b0 = row0 & 511;
    const int t = t0 + tl;

    // stage x rows b0..b0+31 (128 floats each): thread (r=tid>>3, c=tid&7), 4 float4 each
    {
        const int r = tid >> 3, c = tid & 7;
        const float4* xsrc = (const float4*)(x + ((size_t)(b0 + r) * TT + t) * II);
        #pragma unroll
        for (int l = 0; l < 4; ++l) {
            int i4 = c + 8 * l;           // float4 index along i
            float4 v = xsrc[i4];
            xt[i4 * 4 + 0][r] = v.x;
            xt[i4 * 4 + 1][r] = v.y;
            xt[i4 * 4 + 2][r] = v.z;
            xt[i4 * 4 + 3][r] = v.w;
        }
    }
    __syncthreads();

    const int g = tid;
    if (g < GG) {
        float acc[32];
        #pragma unroll
        for (int r2 = 0; r2 < 32; ++r2) acc[r2] = 0.f;
        const float4* wrow = (const float4*)(W_ih + (size_t)g * II);
        #pragma unroll 2
        for (int i4 = 0; i4 < 32; ++i4) {
            float4 w = wrow[i4];
            #pragma unroll
            for (int r4 = 0; r4 < 8; ++r4) {
                float4 x0 = *(const float4*)&xt[i4 * 4 + 0][r4 * 4];
                float4 x1 = *(const float4*)&xt[i4 * 4 + 1][r4 * 4];
                float4 x2 = *(const float4*)&xt[i4 * 4 + 2][r4 * 4];
                float4 x3 = *(const float4*)&xt[i4 * 4 + 3][r4 * 4];
                acc[r4 * 4 + 0] += x0.x * w.x + x1.x * w.y + x2.x * w.z + x3.x * w.w;
                acc[r4 * 4 + 1] += x0.y * w.x + x1.y * w.y + x2.y * w.z + x3.y * w.w;
                acc[r4 * 4 + 2] += x0.z * w.x + x1.z * w.y + x2.z * w.z + x3.z * w.w;
                acc[r4 * 4 + 3] += x0.w * w.x + x1.w * w.y + x2.w * w.z + x3.w * w.w;
            }
        }
        size_t obase = ((size_t)tl * BB + b0) * GG + g;
        #pragma unroll
        for (int r2 = 0; r2 < 32; ++r2)
            xp[obase + (size_t)r2 * GG] = acc[r2];
    }
}

// ---------------- Kernel 2: recurrence ----------------
// One block (1 wave, 64 threads) per batch element. Thread k<50 owns gate rows
// k, k+50, k+100, k+150 in registers (~208 VGPRs); h broadcast via LDS; c in a
// register; next-step xp prefetched under the 200-FMA dot.
__global__ __launch_bounds__(64, 1) void lstm_rec(
    const float* __restrict__ xp, const float* __restrict__ W_hh,
    const float* __restrict__ b_ih, const float* __restrict__ b_hh,
    float* __restrict__ hs, float* __restrict__ cs, int Tc, int first)
{
    __shared__ __align__(16) float h[52];
    const int b = blockIdx.x;
    const int k = threadIdx.x;
    const int kk = (k < HH) ? k : 0;   // clamp idle lanes to safe addresses

    float wI[52], wF[52], wG[52], wO[52];
    #pragma unroll
    for (int j2 = 0; j2 < 25; ++j2) {
        float2 vi = *(const float2*)(W_hh + (size_t)(kk)        * HH + 2 * j2);
        float2 vf = *(const float2*)(W_hh + (size_t)(kk + 50)   * HH + 2 * j2);
        float2 vg = *(const float2*)(W_hh + (size_t)(kk + 100)  * HH + 2 * j2);
        float2 vo = *(const float2*)(W_hh + (size_t)(kk + 150)  * HH + 2 * j2);
        wI[2 * j2] = vi.x; wI[2 * j2 + 1] = vi.y;
        wF[2 * j2] = vf.x; wF[2 * j2 + 1] = vf.y;
        wG[2 * j2] = vg.x; wG[2 * j2 + 1] = vg.y;
        wO[2 * j2] = vo.x; wO[2 * j2 + 1] = vo.y;
    }
    wI[50] = wI[51] = 0.f; wF[50] = wF[51] = 0.f;
    wG[50] = wG[51] = 0.f; wO[50] = wO[51] = 0.f;

    const float biasI = b_ih[kk]       + b_hh[kk];
    const float biasF = b_ih[kk + 50]  + b_hh[kk + 50];
    const float biasG = b_ih[kk + 100] + b_hh[kk + 100];
    const float biasO = b_ih[kk + 150] + b_hh[kk + 150];

    float c = first ? 0.f : cs[b * HH + kk];
    if (k < 52) h[k] = (k < HH) ? (first ? 0.f : hs[b * HH + k]) : 0.f;
    __syncthreads();

    const float* xrow0 = xp + (size_t)b * GG;
    float xi = xrow0[kk], xf = xrow0[kk + 50], xg = xrow0[kk + 100], xo = xrow0[kk + 150];

    for (int t = 0; t < Tc; ++t) {
        const int tn = (t + 1 < Tc) ? (t + 1) : t;
        const float* xn = xp + ((size_t)tn * BB + b) * GG;
        float pi = xn[kk], pf = xn[kk + 50], pg = xn[kk + 100], po = xn[kk + 150];

        float aI = xi + biasI, aF = xf + biasF, aG = xg + biasG, aO = xo + biasO;
        #pragma unroll
        for (int j4 = 0; j4 < 13; ++j4) {
            float4 hv = *(const float4*)&h[4 * j4];
            aI += hv.x * wI[4 * j4] + hv.y * wI[4 * j4 + 1] + hv.z * wI[4 * j4 + 2] + hv.w * wI[4 * j4 + 3];
            aF += hv.x * wF[4 * j4] + hv.y * wF[4 * j4 + 1] + hv.z * wF[4 * j4 + 2] + hv.w * wF[4 * j4 + 3];
            aG += hv.x * wG[4 * j4] + hv.y * wG[4 * j4 + 1] + hv.z * wG[4 * j4 + 2] + hv.w * wG[4 * j4 + 3];
            aO += hv.x * wO[4 * j4] + hv.y * wO[4 * j4 + 1] + hv.z * wO[4 * j4 + 2] + hv.w * wO[4 * j4 + 3];
        }
        float ii = fsig(aI), ff = fsig(aF), gg = ftanh(aG), oo = fsig(aO);
        c = ff * c + ii * gg;
        float hn = oo * ftanh(c);
        __syncthreads();                 // single wave: cheap
        if (k < HH) h[k] = hn;
        __syncthreads();
        xi = pi; xf = pf; xg = pg; xo = po;
    }
    if (k < HH) {
        hs[b * HH + k] = h[k];
        cs[b * HH + k] = c;
    }
}

// ---------------- Kernel 3: FC epilogue ----------------
__global__ __launch_bounds__(256) void fc_kernel(
    const float* __restrict__ hs, const float* __restrict__ W_fc,
    const float* __restrict__ b_fc, float* __restrict__ out)
{
    int idx = blockIdx.x * blockDim.x + threadIdx.x;   // 512*10
    if (idx < BB * 10) {
        int b = idx / 10, o = idx % 10;
        float a = b_fc[o];
        #pragma unroll
        for (int kx = 0; kx < HH; ++kx)
            a += hs[b * HH + kx] * W_fc[o * HH + kx];
        out[idx] = a;
    }
}

extern "C" void kernel_launch(void* const* d_in, const int* in_sizes, int n_in,
                              void* d_out, int out_size, void* d_ws, size_t ws_size,
                              hipStream_t stream)
{
    const float* x    = (const float*)d_in[0];
    const float* W_ih = (const float*)d_in[1];
    const float* W_hh = (const float*)d_in[2];
    const float* b_ih = (const float*)d_in[3];
    const float* b_hh = (const float*)d_in[4];
    const float* W_fc = (const float*)d_in[5];
    const float* b_fc = (const float*)d_in[6];
    float* out = (float*)d_out;
    float* wsf = (float*)d_ws;

    const size_t state_bytes = (size_t)2 * BB * HH * sizeof(float);
    int Tc = TT;
    while (Tc > 1 && (size_t)BB * Tc * GG * sizeof(float) + state_bytes > ws_size)
        Tc >>= 1;

    float* xp = wsf;
    float* hsbuf = wsf + (size_t)BB * Tc * GG;
    float* csbuf = hsbuf + (size_t)BB * HH;

    const int nch = TT / Tc;
    for (int j = 0; j < nch; ++j) {
        xproj_kernel<<<(BB * Tc) / 32, 256, 0, stream>>>(x, W_ih, xp, j * Tc);
        lstm_rec<<<BB, 64, 0, stream>>>(xp, W_hh, b_ih, b_hh, hsbuf, csbuf, Tc, j == 0);
    }
    fc_kernel<<<(BB * 10 + 255) / 256, 256, 0, stream>>>(hsbuf, W_fc, b_fc, out);
}

// Round 2
// 791.516 us; speedup vs baseline: 1.3050x; 1.3050x over previous
//
#include <hip/hip_runtime.h>
#include <hip/hip_bf16.h>

// LSTM: B=512, T=512, I=128, H=50, O=10, fp32.
// R2: gate-parallel recurrence. 256 thr/block, thread g owns W_hh row g
// (50 regs, no spill — R1 spilled at 152 VGPR vs 208+ needed). Gate exchange
// via LDS act[200]; threads k<50 own c_k/h_k tail. Branchless activations.

#define BB 512
#define TT 512
#define II 128
#define HH 50
#define GG 200   // 4*H

__device__ __forceinline__ float fsig(float x) {
    return 1.f / (1.f + __expf(-x));
}
__device__ __forceinline__ float ftanh_pos(float c) {   // tanh via sigmoid
    return 2.f * fsig(2.f * c) - 1.f;
}

// ---------------- Kernel 1: input projection ----------------
// Block: 256 threads, 32 rows (t_local*512 + b) x 200 cols.
// x tile staged transposed in LDS [i][r] (pad 36): inner reads broadcast.
__global__ __launch_bounds__(256) void xproj_kernel(
    const float* __restrict__ x, const float* __restrict__ W_ih,
    float* __restrict__ xp, int t0)
{
    __shared__ __align__(16) float xt[128][36];
    const int tid = threadIdx.x;
    const int row0 = blockIdx.x * 32;     // row = tl*512 + b  (32 | 512)
    const int tl = row0 >> 9;
    const int b0 = row0 & 511;
    const int t = t0 + tl;

    {
        const int r = tid >> 3, c = tid & 7;
        const float4* xsrc = (const float4*)(x + ((size_t)(b0 + r) * TT + t) * II);
        #pragma unroll
        for (int l = 0; l < 4; ++l) {
            int i4 = c + 8 * l;
            float4 v = xsrc[i4];
            xt[i4 * 4 + 0][r] = v.x;
            xt[i4 * 4 + 1][r] = v.y;
            xt[i4 * 4 + 2][r] = v.z;
            xt[i4 * 4 + 3][r] = v.w;
        }
    }
    __syncthreads();

    const int g = tid;
    if (g < GG) {
        float acc[32];
        #pragma unroll
        for (int r2 = 0; r2 < 32; ++r2) acc[r2] = 0.f;
        const float4* wrow = (const float4*)(W_ih + (size_t)g * II);
        #pragma unroll 2
        for (int i4 = 0; i4 < 32; ++i4) {
            float4 w = wrow[i4];
            #pragma unroll
            for (int r4 = 0; r4 < 8; ++r4) {
                float4 x0 = *(const float4*)&xt[i4 * 4 + 0][r4 * 4];
                float4 x1 = *(const float4*)&xt[i4 * 4 + 1][r4 * 4];
                float4 x2 = *(const float4*)&xt[i4 * 4 + 2][r4 * 4];
                float4 x3 = *(const float4*)&xt[i4 * 4 + 3][r4 * 4];
                acc[r4 * 4 + 0] += x0.x * w.x + x1.x * w.y + x2.x * w.z + x3.x * w.w;
                acc[r4 * 4 + 1] += x0.y * w.x + x1.y * w.y + x2.y * w.z + x3.y * w.w;
                acc[r4 * 4 + 2] += x0.z * w.x + x1.z * w.y + x2.z * w.z + x3.z * w.w;
                acc[r4 * 4 + 3] += x0.w * w.x + x1.w * w.y + x2.w * w.z + x3.w * w.w;
            }
        }
        size_t obase = ((size_t)tl * BB + b0) * GG + g;
        #pragma unroll
        for (int r2 = 0; r2 < 32; ++r2)
            xp[obase + (size_t)r2 * GG] = acc[r2];
    }
}

// ---------------- Kernel 2: recurrence (gate-parallel) ----------------
// One block (256 thr = 4 waves) per batch. Thread g<200 owns W_hh row g in
// 52 regs (pad 0). Per step: dot over h (13 broadcast ds_read_b128), branchless
// activation, LDS exchange, threads k<50 update c,h.
__global__ __launch_bounds__(256, 2) void lstm_rec(
    const float* __restrict__ xp, const float* __restrict__ W_hh,
    const float* __restrict__ b_ih, const float* __restrict__ b_hh,
    float* __restrict__ hs, float* __restrict__ cs, int Tc, int first)
{
    __shared__ __align__(16) float hbuf[52];
    __shared__ float act[GG];
    const int b = blockIdx.x;
    const int g = threadIdx.x;
    const bool active = (g < GG);
    const int gg = active ? g : 0;

    float w[52];
    #pragma unroll
    for (int j = 0; j < 25; ++j) {
        float2 v = *(const float2*)(W_hh + (size_t)gg * HH + 2 * j);
        w[2 * j] = v.x; w[2 * j + 1] = v.y;
    }
    w[50] = w[51] = 0.f;

    const float bias = b_ih[gg] + b_hh[gg];
    // rows 100..149 are the g-gate (tanh); others sigmoid. tanh(x)=2*sig(2x)-1.
    const bool is_tanh = (g >= 100 && g < 150);
    const float escale = is_tanh ? 2.f : 1.f;
    const float amul   = is_tanh ? 2.f : 1.f;
    const float aadd   = is_tanh ? -1.f : 0.f;

    float c = 0.f;
    if (g < 52) hbuf[g] = 0.f;
    if (!first && g < HH) {
        c = cs[b * HH + g];
        hbuf[g] = hs[b * HH + g];
    }
    __syncthreads();

    const float* xpb = xp + (size_t)b * GG + gg;
    float xv = xpb[0];

    for (int t = 0; t < Tc; ++t) {
        const int tn = (t + 1 < Tc) ? (t + 1) : t;
        float xnext = xpb[(size_t)tn * BB * GG];

        float a = xv + bias;
        #pragma unroll
        for (int j4 = 0; j4 < 13; ++j4) {
            float4 hv = *(const float4*)&hbuf[4 * j4];
            a += hv.x * w[4 * j4] + hv.y * w[4 * j4 + 1]
               + hv.z * w[4 * j4 + 2] + hv.w * w[4 * j4 + 3];
        }
        float y  = 1.f / (1.f + __expf(-escale * a));
        float av = amul * y + aadd;
        if (active) act[g] = av;
        __syncthreads();
        if (g < HH) {
            float fi = act[g];
            float ff = act[g + 50];
            float fg = act[g + 100];
            float fo = act[g + 150];
            c = ff * c + fi * fg;
            hbuf[g] = fo * ftanh_pos(c);
        }
        __syncthreads();
        xv = xnext;
    }
    if (g < HH) {
        hs[b * HH + g] = hbuf[g];
        cs[b * HH + g] = c;
    }
}

// ---------------- Kernel 3: FC epilogue ----------------
__global__ __launch_bounds__(256) void fc_kernel(
    const float* __restrict__ hs, const float* __restrict__ W_fc,
    const float* __restrict__ b_fc, float* __restrict__ out)
{
    int idx = blockIdx.x * blockDim.x + threadIdx.x;   // 512*10
    if (idx < BB * 10) {
        int b = idx / 10, o = idx % 10;
        float a = b_fc[o];
        #pragma unroll
        for (int kx = 0; kx < HH; ++kx)
            a += hs[b * HH + kx] * W_fc[o * HH + kx];
        out[idx] = a;
    }
}

extern "C" void kernel_launch(void* const* d_in, const int* in_sizes, int n_in,
                              void* d_out, int out_size, void* d_ws, size_t ws_size,
                              hipStream_t stream)
{
    const float* x    = (const float*)d_in[0];
    const float* W_ih = (const float*)d_in[1];
    const float* W_hh = (const float*)d_in[2];
    const float* b_ih = (const float*)d_in[3];
    const float* b_hh = (const float*)d_in[4];
    const float* W_fc = (const float*)d_in[5];
    const float* b_fc = (const float*)d_in[6];
    float* out = (float*)d_out;
    float* wsf = (float*)d_ws;

    const size_t state_bytes = (size_t)2 * BB * HH * sizeof(float);
    int Tc = TT;
    while (Tc > 1 && (size_t)BB * Tc * GG * sizeof(float) + state_bytes > ws_size)
        Tc >>= 1;

    float* xp = wsf;
    float* hsbuf = wsf + (size_t)BB * Tc * GG;
    float* csbuf = hsbuf + (size_t)BB * HH;

    const int nch = TT / Tc;
    for (int j = 0; j < nch; ++j) {
        xproj_kernel<<<(BB * Tc) / 32, 256, 0, stream>>>(x, W_ih, xp, j * Tc);
        lstm_rec<<<BB, 256, 0, stream>>>(xp, W_hh, b_ih, b_hh, hsbuf, csbuf, Tc, j == 0);
    }
    fc_kernel<<<(BB * 10 + 255) / 256, 256, 0, stream>>>(hsbuf, W_fc, b_fc, out);
}

// Round 3
// 585.601 us; speedup vs baseline: 1.7639x; 1.3516x over previous
//
#include <hip/hip_runtime.h>
#include <hip/hip_bf16.h>

// LSTM: B=512, T=512, I=128, H=50, O=10, fp32.
// R3: (1) xproj via f16 MFMA 16x16x32 (W_ih pre-converted to B-fragment order,
// x staged to LDS in A-fragment order, conflict-free); (2) recurrence
// wave-per-batch, thread k owns gates {k,k+50,k+100,k+150} with f16 weights
// consumed by v_dot2_f32_f16 (112 VGPR, no spill — R1's fp32 version spilled).

#define BB 512
#define TT 512
#define II 128
#define HH 50
#define GG 200   // 4*H

typedef _Float16 half2v __attribute__((ext_vector_type(2)));
typedef _Float16 half4v __attribute__((ext_vector_type(4)));
typedef _Float16 half8v __attribute__((ext_vector_type(8)));
typedef float float4v __attribute__((ext_vector_type(4)));

#if defined(__has_builtin)
#if __has_builtin(__builtin_amdgcn_fdot2)
#define HAVE_FDOT2 1
#endif
#endif

__device__ __forceinline__ float fdot2f(half2v a, half2v b, float c) {
#ifdef HAVE_FDOT2
    return __builtin_amdgcn_fdot2(a, b, c, false);
#else
    return c + (float)a[0] * (float)b[0] + (float)a[1] * (float)b[1];
#endif
}

__device__ __forceinline__ float fsig(float x) {
    return 1.f / (1.f + __expf(-x));
}
__device__ __forceinline__ float ftanh(float x) {   // tanh via sigmoid, saturates correctly
    return 2.f * fsig(2.f * x) - 1.f;
}

// ---------------- Kernel 0: prep (once per launch) ----------------
// wfrags: W_ih as f16 MFMA B-fragments [nt 13][kc 4][lane 64][j 8]
// whh16:  W_hh rows padded to 56 f16   [g 200][56]
// biasv:  b_ih + b_hh                  [g 200]
__global__ __launch_bounds__(256) void prep_kernel(
    const float* __restrict__ W_ih, const float* __restrict__ W_hh,
    const float* __restrict__ b_ih, const float* __restrict__ b_hh,
    _Float16* __restrict__ wfrags, _Float16* __restrict__ whh16,
    float* __restrict__ biasv)
{
    int idx = blockIdx.x * 256 + threadIdx.x;
    if (idx < 3328) {                       // 13*4*64 fragment slots
        int lane = idx & 63, kc = (idx >> 6) & 3, nt = idx >> 8;
        int g = nt * 16 + (lane & 15);
        int k0 = kc * 32 + ((lane >> 4) & 3) * 8;
        half8v v;
        #pragma unroll
        for (int j = 0; j < 8; ++j)
            v[j] = (g < GG) ? (_Float16)W_ih[g * II + k0 + j] : (_Float16)0.f;
        *(half8v*)(wfrags + (size_t)idx * 8) = v;
    } else if (idx < 3328 + 2800) {         // 200 rows * 14 quads
        int r = idx - 3328;
        int g = r / 14, j4 = r % 14;
        #pragma unroll
        for (int j = 0; j < 4; ++j) {
            int hidx = j4 * 4 + j;
            whh16[g * 56 + hidx] = (hidx < HH) ? (_Float16)W_hh[g * HH + hidx]
                                               : (_Float16)0.f;
        }
    } else if (idx < 3328 + 2800 + GG) {
        int g = idx - 6128;
        biasv[g] = b_ih[g] + b_hh[g];
    }
}

// ---------------- Kernel 1: xproj via MFMA ----------------
// Block: 256 thr (4 waves), M-tile 64 rows (one t, 64 batches), N=208 (13 nt),
// K=128 (4 kc of 32). A staged in LDS in fragment order; B fragments from L2.
__global__ __launch_bounds__(256) void xproj_mfma(
    const float* __restrict__ x, const _Float16* __restrict__ wfrags,
    float* __restrict__ xp, int t0)
{
    __shared__ __align__(16) _Float16 afrag[4 * 4 * 64 * 8];  // [wr][kc][lane][j] 16 KB
    const int tid = threadIdx.x;
    const int row0 = blockIdx.x * 64;       // rows = tl*512 + b; 64 | 512
    const int tl = row0 >> 9;
    const int b0 = row0 & 511;
    const int t = t0 + tl;

    // Stage A: thread covers dwords d=it*512+2*tid, d+1 (same lane, k0..k0+3).
    #pragma unroll
    for (int it = 0; it < 8; ++it) {
        int d = it * 512 + tid * 2;
        int lane = (d >> 2) & 63, kc = (d >> 8) & 3, wr = d >> 10;
        int jd = d & 3;                      // 0 or 2
        int row = wr * 16 + (lane & 15);
        int k0 = kc * 32 + ((lane >> 4) & 3) * 8 + jd * 2;
        const float4 v = *(const float4*)(x + ((size_t)(b0 + row) * TT + t) * II + k0);
        half4v p = { (_Float16)v.x, (_Float16)v.y, (_Float16)v.z, (_Float16)v.w };
        *(half4v*)(afrag + d * 2) = p;       // stride-1 b64 writes: conflict-free
    }
    __syncthreads();

    const int w = tid >> 6;
    const int l = tid & 63;
    float4v acc[13];
    #pragma unroll
    for (int nt = 0; nt < 13; ++nt) acc[nt] = (float4v){0.f, 0.f, 0.f, 0.f};

    #pragma unroll
    for (int kc = 0; kc < 4; ++kc) {
        half8v a = *(half8v*)(afrag + (((w * 4 + kc) * 64) + l) * 8);
        #pragma unroll
        for (int nt = 0; nt < 13; ++nt) {
            half8v bf = *(const half8v*)(wfrags + (size_t)(((nt * 4 + kc) * 64) + l) * 8);
            acc[nt] = __builtin_amdgcn_mfma_f32_16x16x32_f16(a, bf, acc[nt], 0, 0, 0);
        }
    }

    // Epilogue: C/D layout col=lane&15, row=(lane>>4)*4+reg
    const int colb = l & 15, rquad = l >> 4;
    #pragma unroll
    for (int nt = 0; nt < 13; ++nt) {
        int g = nt * 16 + colb;
        if (g < GG) {
            #pragma unroll
            for (int reg = 0; reg < 4; ++reg) {
                int grow = row0 + w * 16 + rquad * 4 + reg;
                xp[(size_t)grow * GG + g] = acc[nt][reg];
            }
        }
    }
}

// ---------------- Kernel 2: recurrence (wave-per-batch) ----------------
// 64 thr = 1 wave per batch. Thread k<50 owns gates {k,k+50,k+100,k+150}:
// weights 4x7 half8 = 112 VGPR; h as f16 in LDS (7 broadcast b128 reads/step);
// c,h update thread-local (no gate exchange).
__global__ __launch_bounds__(64, 1) void lstm_rec(
    const float* __restrict__ xp, const _Float16* __restrict__ whh16,
    const float* __restrict__ biasv,
    float* __restrict__ hs, float* __restrict__ cs, int Tc, int first)
{
    __shared__ __align__(16) _Float16 hbuf[64];
    const int b = blockIdx.x;
    const int k = threadIdx.x;
    const int kk = (k < HH) ? k : 0;

    half8v wr0[7], wr1[7], wr2[7], wr3[7];
    #pragma unroll
    for (int j = 0; j < 7; ++j) {
        wr0[j] = *(const half8v*)(whh16 + (size_t)(kk      ) * 56 + j * 8);
        wr1[j] = *(const half8v*)(whh16 + (size_t)(kk +  50) * 56 + j * 8);
        wr2[j] = *(const half8v*)(whh16 + (size_t)(kk + 100) * 56 + j * 8);
        wr3[j] = *(const half8v*)(whh16 + (size_t)(kk + 150) * 56 + j * 8);
    }
    const float bi = biasv[kk], bf2 = biasv[kk + 50],
                bg = biasv[kk + 100], bo = biasv[kk + 150];

    float c = (!first && k < HH) ? cs[b * HH + kk] : 0.f;
    hbuf[k] = (_Float16)0.f;
    if (!first && k < HH) hbuf[k] = (_Float16)hs[b * HH + k];
    __syncthreads();

    const float* xpb = xp + (size_t)b * GG;
    float xi = xpb[kk], xf = xpb[kk + 50], xg = xpb[kk + 100], xo = xpb[kk + 150];
    float hlast = 0.f;

    for (int t = 0; t < Tc; ++t) {
        const int tn = (t + 1 < Tc) ? (t + 1) : t;
        const float* xn = xpb + (size_t)tn * BB * GG;
        float pi = xn[kk], pf = xn[kk + 50], pg = xn[kk + 100], po = xn[kk + 150];

        half8v hv[7];
        #pragma unroll
        for (int j = 0; j < 7; ++j) hv[j] = *(half8v*)(hbuf + j * 8);

        float aI = xi + bi, aF = xf + bf2, aG = xg + bg, aO = xo + bo;
        #pragma unroll
        for (int j = 0; j < 7; ++j) {
            half2v* hp = (half2v*)&hv[j];
            #pragma unroll
            for (int q = 0; q < 4; ++q) {
                half2v hq = hp[q];
                aI = fdot2f(hq, ((half2v*)&wr0[j])[q], aI);
                aF = fdot2f(hq, ((half2v*)&wr1[j])[q], aF);
                aG = fdot2f(hq, ((half2v*)&wr2[j])[q], aG);
                aO = fdot2f(hq, ((half2v*)&wr3[j])[q], aO);
            }
        }
        float ii = fsig(aI), ff = fsig(aF), gg = ftanh(aG), oo = fsig(aO);
        c = ff * c + ii * gg;
        float hn = oo * ftanh(c);
        __syncthreads();
        if (k < HH) hbuf[k] = (_Float16)hn;
        __syncthreads();
        xi = pi; xf = pf; xg = pg; xo = po;
        hlast = hn;
    }
    if (k < HH) {
        hs[b * HH + k] = hlast;
        cs[b * HH + k] = c;
    }
}

// ---------------- Kernel 3: FC epilogue ----------------
__global__ __launch_bounds__(256) void fc_kernel(
    const float* __restrict__ hs, const float* __restrict__ W_fc,
    const float* __restrict__ b_fc, float* __restrict__ out)
{
    int idx = blockIdx.x * blockDim.x + threadIdx.x;   // 512*10
    if (idx < BB * 10) {
        int b = idx / 10, o = idx % 10;
        float a = b_fc[o];
        #pragma unroll
        for (int kx = 0; kx < HH; ++kx)
            a += hs[b * HH + kx] * W_fc[o * HH + kx];
        out[idx] = a;
    }
}

extern "C" void kernel_launch(void* const* d_in, const int* in_sizes, int n_in,
                              void* d_out, int out_size, void* d_ws, size_t ws_size,
                              hipStream_t stream)
{
    const float* x    = (const float*)d_in[0];
    const float* W_ih = (const float*)d_in[1];
    const float* W_hh = (const float*)d_in[2];
    const float* b_ih = (const float*)d_in[3];
    const float* b_hh = (const float*)d_in[4];
    const float* W_fc = (const float*)d_in[5];
    const float* b_fc = (const float*)d_in[6];
    float* out = (float*)d_out;
    char* wsb = (char*)d_ws;

    // fixed region: hs, cs, wfrags, whh16, biasv
    const size_t hs_b = (size_t)BB * HH * sizeof(float);        // 102400
    const size_t wfrags_b = (size_t)13 * 4 * 64 * 8 * 2;        // 53248
    const size_t whh_b = (size_t)GG * 56 * 2;                   // 22400
    const size_t bias_b = 1024;
    const size_t fixed_b = 2 * hs_b + wfrags_b + whh_b + bias_b;

    int Tc = TT;
    while (Tc > 1 && (size_t)BB * Tc * GG * sizeof(float) + fixed_b > ws_size)
        Tc >>= 1;

    float* xp = (float*)wsb;
    char* p = wsb + (size_t)BB * Tc * GG * sizeof(float);
    float* hsbuf = (float*)p;            p += hs_b;
    float* csbuf = (float*)p;            p += hs_b;
    _Float16* wfrags = (_Float16*)p;     p += wfrags_b;
    _Float16* whh16 = (_Float16*)p;      p += whh_b;
    float* biasv = (float*)p;

    prep_kernel<<<25, 256, 0, stream>>>(W_ih, W_hh, b_ih, b_hh, wfrags, whh16, biasv);

    const int nch = TT / Tc;
    for (int j = 0; j < nch; ++j) {
        xproj_mfma<<<(BB * Tc) / 64, 256, 0, stream>>>(x, wfrags, xp, j * Tc);
        lstm_rec<<<BB, 64, 0, stream>>>(xp, whh16, biasv, hsbuf, csbuf, Tc, j == 0);
    }
    fc_kernel<<<(BB * 10 + 255) / 256, 256, 0, stream>>>(hsbuf, W_fc, b_fc, out);
}

// Round 4
// 502.024 us; speedup vs baseline: 2.0576x; 1.1665x over previous
//
#include <hip/hip_runtime.h>
#include <hip/hip_bf16.h>

// LSTM: B=512, T=512, I=128, H=50, O=10, fp32.
// R4: (1) lstm_rec gets a 4-deep circular register prefetch of xp — R3 was
// latency-bound (1524 cyc/step vs ~350 issue; 1-step prefetch < 900-cyc HBM
// latency at 2 waves/CU). (2) xp stored as f16: halves xproj write traffic
// and lstm fetch. Weights stay f16-packed in VGPRs (R3: VGPR=72, no spill).

#define BB 512
#define TT 512
#define II 128
#define HH 50
#define GG 200   // 4*H

typedef _Float16 half2v __attribute__((ext_vector_type(2)));
typedef _Float16 half4v __attribute__((ext_vector_type(4)));
typedef _Float16 half8v __attribute__((ext_vector_type(8)));
typedef float float4v __attribute__((ext_vector_type(4)));

#if defined(__has_builtin)
#if __has_builtin(__builtin_amdgcn_fdot2)
#define HAVE_FDOT2 1
#endif
#endif

__device__ __forceinline__ float fdot2f(half2v a, half2v b, float c) {
#ifdef HAVE_FDOT2
    return __builtin_amdgcn_fdot2(a, b, c, false);
#else
    return c + (float)a[0] * (float)b[0] + (float)a[1] * (float)b[1];
#endif
}

__device__ __forceinline__ float fsig(float x) {
    return 1.f / (1.f + __expf(-x));
}
__device__ __forceinline__ float ftanh(float x) {
    return 2.f * fsig(2.f * x) - 1.f;
}

// ---------------- Kernel 0: prep (once per launch) ----------------
// wfrags: W_ih as f16 MFMA B-fragments [nt 13][kc 4][lane 64][j 8]
// whh16:  W_hh rows padded to 56 f16   [g 200][56]
// biasv:  b_ih + b_hh                  [g 200]
__global__ __launch_bounds__(256) void prep_kernel(
    const float* __restrict__ W_ih, const float* __restrict__ W_hh,
    const float* __restrict__ b_ih, const float* __restrict__ b_hh,
    _Float16* __restrict__ wfrags, _Float16* __restrict__ whh16,
    float* __restrict__ biasv)
{
    int idx = blockIdx.x * 256 + threadIdx.x;
    if (idx < 3328) {                       // 13*4*64 fragment slots
        int lane = idx & 63, kc = (idx >> 6) & 3, nt = idx >> 8;
        int g = nt * 16 + (lane & 15);
        int k0 = kc * 32 + ((lane >> 4) & 3) * 8;
        half8v v;
        #pragma unroll
        for (int j = 0; j < 8; ++j)
            v[j] = (g < GG) ? (_Float16)W_ih[g * II + k0 + j] : (_Float16)0.f;
        *(half8v*)(wfrags + (size_t)idx * 8) = v;
    } else if (idx < 3328 + 2800) {         // 200 rows * 14 quads
        int r = idx - 3328;
        int g = r / 14, j4 = r % 14;
        #pragma unroll
        for (int j = 0; j < 4; ++j) {
            int hidx = j4 * 4 + j;
            whh16[g * 56 + hidx] = (hidx < HH) ? (_Float16)W_hh[g * HH + hidx]
                                               : (_Float16)0.f;
        }
    } else if (idx < 3328 + 2800 + GG) {
        int g = idx - 6128;
        biasv[g] = b_ih[g] + b_hh[g];
    }
}

// ---------------- Kernel 1: xproj via MFMA, f16 output ----------------
__global__ __launch_bounds__(256) void xproj_mfma(
    const float* __restrict__ x, const _Float16* __restrict__ wfrags,
    _Float16* __restrict__ xp16, int t0)
{
    __shared__ __align__(16) _Float16 afrag[4 * 4 * 64 * 8];  // 16 KB
    const int tid = threadIdx.x;
    const int row0 = blockIdx.x * 64;       // rows = tl*512 + b; 64 | 512
    const int tl = row0 >> 9;
    const int b0 = row0 & 511;
    const int t = t0 + tl;

    #pragma unroll
    for (int it = 0; it < 8; ++it) {
        int d = it * 512 + tid * 2;
        int lane = (d >> 2) & 63, kc = (d >> 8) & 3, wr = d >> 10;
        int jd = d & 3;                      // 0 or 2
        int row = wr * 16 + (lane & 15);
        int k0 = kc * 32 + ((lane >> 4) & 3) * 8 + jd * 2;
        const float4 v = *(const float4*)(x + ((size_t)(b0 + row) * TT + t) * II + k0);
        half4v p = { (_Float16)v.x, (_Float16)v.y, (_Float16)v.z, (_Float16)v.w };
        *(half4v*)(afrag + d * 2) = p;
    }
    __syncthreads();

    const int w = tid >> 6;
    const int l = tid & 63;
    float4v acc[13];
    #pragma unroll
    for (int nt = 0; nt < 13; ++nt) acc[nt] = (float4v){0.f, 0.f, 0.f, 0.f};

    #pragma unroll
    for (int kc = 0; kc < 4; ++kc) {
        half8v a = *(half8v*)(afrag + (((w * 4 + kc) * 64) + l) * 8);
        #pragma unroll
        for (int nt = 0; nt < 13; ++nt) {
            half8v bf = *(const half8v*)(wfrags + (size_t)(((nt * 4 + kc) * 64) + l) * 8);
            acc[nt] = __builtin_amdgcn_mfma_f32_16x16x32_f16(a, bf, acc[nt], 0, 0, 0);
        }
    }

    // C/D layout: col=lane&15, row=(lane>>4)*4+reg
    const int colb = l & 15, rquad = l >> 4;
    #pragma unroll
    for (int nt = 0; nt < 13; ++nt) {
        int g = nt * 16 + colb;
        if (g < GG) {
            #pragma unroll
            for (int reg = 0; reg < 4; ++reg) {
                int grow = row0 + w * 16 + rquad * 4 + reg;
                xp16[(size_t)grow * GG + g] = (_Float16)acc[nt][reg];
            }
        }
    }
}

// ---------------- Kernel 2: recurrence (wave-per-batch, 4-deep prefetch) ----
__global__ __launch_bounds__(64, 1) void lstm_rec(
    const _Float16* __restrict__ xp16, const _Float16* __restrict__ whh16,
    const float* __restrict__ biasv,
    float* __restrict__ hs, float* __restrict__ cs, int Tc, int first)
{
    __shared__ __align__(16) _Float16 hbuf[64];
    const int b = blockIdx.x;
    const int k = threadIdx.x;
    const int kk = (k < HH) ? k : 0;

    half8v wr0[7], wr1[7], wr2[7], wr3[7];
    #pragma unroll
    for (int j = 0; j < 7; ++j) {
        wr0[j] = *(const half8v*)(whh16 + (size_t)(kk      ) * 56 + j * 8);
        wr1[j] = *(const half8v*)(whh16 + (size_t)(kk +  50) * 56 + j * 8);
        wr2[j] = *(const half8v*)(whh16 + (size_t)(kk + 100) * 56 + j * 8);
        wr3[j] = *(const half8v*)(whh16 + (size_t)(kk + 150) * 56 + j * 8);
    }
    const float bi = biasv[kk], bf2 = biasv[kk + 50],
                bg = biasv[kk + 100], bo = biasv[kk + 150];

    float c = (!first && k < HH) ? cs[b * HH + kk] : 0.f;
    hbuf[k] = (_Float16)0.f;
    if (!first && k < HH) hbuf[k] = (_Float16)hs[b * HH + k];
    __syncthreads();

    const _Float16* xpb = xp16 + (size_t)b * GG;
    const size_t tstr = (size_t)BB * GG;

    _Float16 pi[4], pf[4], pg[4], po[4];
    #pragma unroll
    for (int d = 0; d < 4; ++d) {
        int td = (d < Tc) ? d : (Tc - 1);
        const _Float16* xn = xpb + (size_t)td * tstr;
        pi[d] = xn[kk]; pf[d] = xn[kk + 50]; pg[d] = xn[kk + 100]; po[d] = xn[kk + 150];
    }

    float hlast = 0.f;
    #pragma unroll 4
    for (int t = 0; t < Tc; ++t) {
        const int s = t & 3;
        float aI = (float)pi[s] + bi;
        float aF = (float)pf[s] + bf2;
        float aG = (float)pg[s] + bg;
        float aO = (float)po[s] + bo;

        // refill slot s for t+4 (in flight across ~4 steps of compute)
        {
            int tn = t + 4; if (tn >= Tc) tn = Tc - 1;
            const _Float16* xn = xpb + (size_t)tn * tstr;
            pi[s] = xn[kk]; pf[s] = xn[kk + 50];
            pg[s] = xn[kk + 100]; po[s] = xn[kk + 150];
        }

        half8v hv[7];
        #pragma unroll
        for (int j = 0; j < 7; ++j) hv[j] = *(half8v*)(hbuf + j * 8);

        #pragma unroll
        for (int j = 0; j < 7; ++j) {
            half2v* hp = (half2v*)&hv[j];
            #pragma unroll
            for (int q = 0; q < 4; ++q) {
                half2v hq = hp[q];
                aI = fdot2f(hq, ((half2v*)&wr0[j])[q], aI);
                aF = fdot2f(hq, ((half2v*)&wr1[j])[q], aF);
                aG = fdot2f(hq, ((half2v*)&wr2[j])[q], aG);
                aO = fdot2f(hq, ((half2v*)&wr3[j])[q], aO);
            }
        }
        float ii = fsig(aI), ff = fsig(aF), gg = ftanh(aG), oo = fsig(aO);
        c = ff * c + ii * gg;
        float hn = oo * ftanh(c);
        __syncthreads();
        if (k < HH) hbuf[k] = (_Float16)hn;
        __syncthreads();
        hlast = hn;
    }
    if (k < HH) {
        hs[b * HH + k] = hlast;
        cs[b * HH + k] = c;
    }
}

// ---------------- Kernel 3: FC epilogue ----------------
__global__ __launch_bounds__(256) void fc_kernel(
    const float* __restrict__ hs, const float* __restrict__ W_fc,
    const float* __restrict__ b_fc, float* __restrict__ out)
{
    int idx = blockIdx.x * blockDim.x + threadIdx.x;   // 512*10
    if (idx < BB * 10) {
        int b = idx / 10, o = idx % 10;
        float a = b_fc[o];
        #pragma unroll
        for (int kx = 0; kx < HH; ++kx)
            a += hs[b * HH + kx] * W_fc[o * HH + kx];
        out[idx] = a;
    }
}

extern "C" void kernel_launch(void* const* d_in, const int* in_sizes, int n_in,
                              void* d_out, int out_size, void* d_ws, size_t ws_size,
                              hipStream_t stream)
{
    const float* x    = (const float*)d_in[0];
    const float* W_ih = (const float*)d_in[1];
    const float* W_hh = (const float*)d_in[2];
    const float* b_ih = (const float*)d_in[3];
    const float* b_hh = (const float*)d_in[4];
    const float* W_fc = (const float*)d_in[5];
    const float* b_fc = (const float*)d_in[6];
    float* out = (float*)d_out;
    char* wsb = (char*)d_ws;

    const size_t hs_b = (size_t)BB * HH * sizeof(float);        // 102400
    const size_t wfrags_b = (size_t)13 * 4 * 64 * 8 * 2;        // 53248
    const size_t whh_b = (size_t)GG * 56 * 2;                   // 22400
    const size_t bias_b = 1024;
    const size_t fixed_b = 2 * hs_b + wfrags_b + whh_b + bias_b;

    int Tc = TT;
    while (Tc > 1 && (size_t)BB * Tc * GG * 2 + fixed_b > ws_size)
        Tc >>= 1;

    _Float16* xp16 = (_Float16*)wsb;
    char* p = wsb + (size_t)BB * Tc * GG * 2;
    float* hsbuf = (float*)p;            p += hs_b;
    float* csbuf = (float*)p;            p += hs_b;
    _Float16* wfrags = (_Float16*)p;     p += wfrags_b;
    _Float16* whh16 = (_Float16*)p;      p += whh_b;
    float* biasv = (float*)p;

    prep_kernel<<<25, 256, 0, stream>>>(W_ih, W_hh, b_ih, b_hh, wfrags, whh16, biasv);

    const int nch = TT / Tc;
    for (int j = 0; j < nch; ++j) {
        xproj_mfma<<<(BB * Tc) / 64, 256, 0, stream>>>(x, wfrags, xp16, j * Tc);
        lstm_rec<<<BB, 64, 0, stream>>>(xp16, whh16, biasv, hsbuf, csbuf, Tc, j == 0);
    }
    fc_kernel<<<(BB * 10 + 255) / 256, 256, 0, stream>>>(hsbuf, W_fc, b_fc, out);
}